// Round 1
// baseline (497.398 us; speedup 1.0000x reference)
//
#include <hip/hip_runtime.h>
#include <cstdint>
#include <cstddef>

#define N 8192
#define F 64
#define NEMB 128
#define TI 16
#define TJ 256
#define LEAKY 0.01f

__device__ __forceinline__ float wave_reduce_max_f(float v){
  #pragma unroll
  for (int d = 32; d > 0; d >>= 1) v = fmaxf(v, __shfl_xor(v, d, 64));
  return v;
}
__device__ __forceinline__ float wave_reduce_sum_f(float v){
  #pragma unroll
  for (int d = 32; d > 0; d >>= 1) v += __shfl_xor(v, d, 64);
  return v;
}
__device__ __forceinline__ int wave_reduce_sum_i(int v){
  #pragma unroll
  for (int d = 32; d > 0; d >>= 1) v += __shfl_xor(v, d, 64);
  return v;
}
__device__ __forceinline__ int wave_incl_scan_i(int v, int lane){
  #pragma unroll
  for (int d = 1; d < 64; d <<= 1){
    int u = __shfl_up(v, d, 64);
    if (lane >= d) v += u;
  }
  return v;
}

// Kernel A: h = x @ W^T + b  (8192x64), s_src[n] = h[n].a_src, s_dst[n] = h[n].a_dst
extern "C" __global__ void __launch_bounds__(256)
k_h(const float* __restrict__ x, const float* __restrict__ ww, const float* __restrict__ wb,
    const float* __restrict__ aw, float* __restrict__ h,
    float* __restrict__ ssrc, float* __restrict__ sdst){
  __shared__ float xs[4][NEMB];
  const int t = threadIdx.x, w = t >> 6, lane = t & 63;
  const int n0 = blockIdx.x * 4;
  // cooperative load of 4 x-rows (512 floats) via float2
  ((float2*)&xs[0][0])[t] = ((const float2*)(x + (size_t)n0 * NEMB))[t];
  __syncthreads();
  const int n = n0 + w;
  const float4* w4 = (const float4*)(ww + (size_t)lane * NEMB);
  const float4* x4 = (const float4*)&xs[w][0];
  float acc = wb[lane];
  #pragma unroll
  for (int k = 0; k < NEMB/4; ++k){
    float4 a = x4[k]; float4 b = w4[k];
    acc = fmaf(a.x, b.x, acc);
    acc = fmaf(a.y, b.y, acc);
    acc = fmaf(a.z, b.z, acc);
    acc = fmaf(a.w, b.w, acc);
  }
  h[(size_t)n * F + lane] = acc;
  float vs = wave_reduce_sum_f(acc * aw[lane]);
  float vd = wave_reduce_sum_f(acc * aw[F + lane]);
  if (lane == 0){ ssrc[n] = vs; sdst[n] = vd; }
}

// Kernel B: per-row masked count
extern "C" __global__ void __launch_bounds__(256)
k_cnt(const int* __restrict__ adj, int* __restrict__ cnt){
  const int i = blockIdx.x, t = threadIdx.x;
  const int4* row = (const int4*)(adj + (size_t)i * N);
  int s = 0;
  #pragma unroll
  for (int k = 0; k < 8; ++k){
    int4 a = row[k * 256 + t];
    s += (a.x > 0) + (a.y > 0) + (a.z > 0) + (a.w > 0);
  }
  s = wave_reduce_sum_i(s);
  __shared__ int ws[4];
  if ((t & 63) == 0) ws[t >> 6] = s;
  __syncthreads();
  if (t == 0) cnt[i] = ws[0] + ws[1] + ws[2] + ws[3];
}

// Kernel C: exclusive scan of 8192 counts -> row_base
extern "C" __global__ void __launch_bounds__(1024)
k_scan(const int* __restrict__ cnt, int* __restrict__ base){
  __shared__ int wsum[16];
  const int t = threadIdx.x, lane = t & 63, w = t >> 6;
  int4 aa = ((const int4*)cnt)[t * 2];
  int4 bb = ((const int4*)cnt)[t * 2 + 1];
  int v[8] = {aa.x, aa.y, aa.z, aa.w, bb.x, bb.y, bb.z, bb.w};
  int local = 0;
  #pragma unroll
  for (int k = 0; k < 8; ++k){ int tmp = v[k]; v[k] = local; local += tmp; }
  int inc = wave_incl_scan_i(local, lane);
  int wexcl = inc - local;
  if (lane == 63) wsum[w] = inc;
  __syncthreads();
  if (t == 0){
    int run = 0;
    #pragma unroll
    for (int k = 0; k < 16; ++k){ int tmp = wsum[k]; wsum[k] = run; run += tmp; }
  }
  __syncthreads();
  const int b0 = wsum[w] + wexcl;
  ((int4*)base)[t * 2]     = make_int4(b0 + v[0], b0 + v[1], b0 + v[2], b0 + v[3]);
  ((int4*)base)[t * 2 + 1] = make_int4(b0 + v[4], b0 + v[5], b0 + v[6], b0 + v[7]);
}

// Kernel D: fused rank + logits + online softmax + att@h + elu
// Block: 256 threads (4 waves). Block covers TI=16 rows; wave w owns rows w*4..w*4+3.
// Lane l owns output feature f=l for its wave's 4 rows.
extern "C" __global__ void __launch_bounds__(256, 2)
k_main(const int* __restrict__ adj, const float* __restrict__ h,
       const float* __restrict__ ssrc, const float* __restrict__ sdst,
       const float* __restrict__ abias, const int* __restrict__ base,
       float* __restrict__ out){
  __shared__ float h_lds[TJ * F];        // 64 KB: h chunk, layout [j][f]
  __shared__ float w_lds[4][4][TJ];      // 16 KB: softmax weights per wave/row
  const int t = threadIdx.x, w = t >> 6, lane = t & 63;
  const int i0 = blockIdx.x * TI;
  const float ab = abias[0];

  float m[4], lsum[4], acc[4];
  int rank[4];
  #pragma unroll
  for (int r = 0; r < 4; ++r){
    m[r] = -INFINITY; lsum[r] = 0.f; acc[r] = 0.f;
    rank[r] = base[i0 + w * 4 + r];
  }

  for (int j0 = 0; j0 < N; j0 += TJ){
    __syncthreads();   // protect h_lds against previous iteration's readers
    // stage h chunk (TJ x F fp32 = 64KB), coalesced float4
    {
      const float4* gsrc = (const float4*)(h + (size_t)j0 * F);
      float4* ldst = (float4*)h_lds;
      #pragma unroll
      for (int it = 0; it < 16; ++it) ldst[it * 256 + t] = gsrc[it * 256 + t];
    }
    // per-row: mask scan -> ranks -> logits -> online softmax -> weights to LDS
    #pragma unroll
    for (int r = 0; r < 4; ++r){
      const int i = i0 + w * 4 + r;
      const int4 a4 = *(const int4*)(adj + (size_t)i * N + j0 + lane * 4);
      const int m0 = a4.x > 0, m1 = a4.y > 0, m2 = a4.z > 0, m3 = a4.w > 0;
      const int cnt = m0 + m1 + m2 + m3;
      const int inc = wave_incl_scan_i(cnt, lane);
      const int total = __shfl(inc, 63, 64);
      int q = rank[r] + inc - cnt;   // global rank of this lane's first masked element
      float lg0 = -INFINITY, lg1 = -INFINITY, lg2 = -INFINITY, lg3 = -INFINITY;
      if (m0){ float e = ssrc[q >> 13] + sdst[q & (N - 1)] + ab; lg0 = (e > 0.f) ? e : LEAKY * e; q++; }
      if (m1){ float e = ssrc[q >> 13] + sdst[q & (N - 1)] + ab; lg1 = (e > 0.f) ? e : LEAKY * e; q++; }
      if (m2){ float e = ssrc[q >> 13] + sdst[q & (N - 1)] + ab; lg2 = (e > 0.f) ? e : LEAKY * e; q++; }
      if (m3){ float e = ssrc[q >> 13] + sdst[q & (N - 1)] + ab; lg3 = (e > 0.f) ? e : LEAKY * e; q++; }
      float lmax = fmaxf(fmaxf(lg0, lg1), fmaxf(lg2, lg3));
      lmax = wave_reduce_max_f(lmax);
      const float newm = fmaxf(m[r], lmax);
      const float scale = (newm == m[r]) ? 1.f : __expf(m[r] - newm);
      const float p0 = m0 ? __expf(lg0 - newm) : 0.f;
      const float p1 = m1 ? __expf(lg1 - newm) : 0.f;
      const float p2 = m2 ? __expf(lg2 - newm) : 0.f;
      const float p3 = m3 ? __expf(lg3 - newm) : 0.f;
      const float psum = wave_reduce_sum_f(p0 + p1 + p2 + p3);
      lsum[r] = lsum[r] * scale + psum;
      acc[r] *= scale;
      m[r] = newm;
      rank[r] += total;
      *(float4*)&w_lds[w][r][lane * 4] = make_float4(p0, p1, p2, p3);
    }
    __syncthreads();   // h_lds fully staged; w_lds is wave-private
    // accumulate: acc[r] += sum_j w[r][j] * h[j][lane]
    #pragma unroll 2
    for (int jq = 0; jq < TJ / 4; ++jq){
      const float h0 = h_lds[(jq * 4 + 0) * F + lane];
      const float h1 = h_lds[(jq * 4 + 1) * F + lane];
      const float h2 = h_lds[(jq * 4 + 2) * F + lane];
      const float h3 = h_lds[(jq * 4 + 3) * F + lane];
      #pragma unroll
      for (int r = 0; r < 4; ++r){
        const float4 wq = *(const float4*)&w_lds[w][r][jq * 4];
        float a = acc[r];
        a = fmaf(wq.x, h0, a);
        a = fmaf(wq.y, h1, a);
        a = fmaf(wq.z, h2, a);
        a = fmaf(wq.w, h3, a);
        acc[r] = a;
      }
    }
  }
  #pragma unroll
  for (int r = 0; r < 4; ++r){
    const float dnm = lsum[r];
    float v = (dnm > 0.f) ? (acc[r] / dnm) : 0.f;
    const float o = (v > 0.f) ? v : (__expf(v) - 1.f);
    out[(size_t)(i0 + w * 4 + r) * F + lane] = o;
  }
}

extern "C" void kernel_launch(void* const* d_in, const int* in_sizes, int n_in,
                              void* d_out, int out_size, void* d_ws, size_t ws_size,
                              hipStream_t stream){
  const float* x  = (const float*)d_in[0];
  const int*   adj = (const int*)d_in[1];
  const float* ww = (const float*)d_in[2];
  const float* wb = (const float*)d_in[3];
  const float* aw = (const float*)d_in[4];
  const float* ab = (const float*)d_in[5];
  float* out = (float*)d_out;

  char* ws = (char*)d_ws;
  float* h    = (float*)(ws);                         // 8192*64*4 = 2 MB
  float* ssrc = (float*)(ws + (size_t)N * F * 4);     // 32 KB
  float* sdst = ssrc + N;                             // 32 KB
  int*   cnt  = (int*)(sdst + N);                     // 32 KB
  int*   base = cnt + N;                              // 32 KB

  k_h  <<<N / 4, 256, 0, stream>>>(x, ww, wb, aw, h, ssrc, sdst);
  k_cnt<<<N,     256, 0, stream>>>(adj, cnt);
  k_scan<<<1,   1024, 0, stream>>>(cnt, base);
  k_main<<<N / TI, 256, 0, stream>>>(adj, h, ssrc, sdst, ab, base, out);
}

// Round 2
// 187.462 us; speedup vs baseline: 2.6533x; 2.6533x over previous
//
#include <hip/hip_runtime.h>
#include <hip/hip_bf16.h>
#include <cstdint>
#include <cstddef>

#define N 8192
#define F 64
#define NEMB 128
#define BI 16
#define BJ 256
#define NWRD (N/16)
#define LEAKY 0.01f

typedef __attribute__((ext_vector_type(8))) short bf16x8;
typedef __attribute__((ext_vector_type(4))) float f32x4;

__device__ __forceinline__ float wave_reduce_sum_f(float v){
  #pragma unroll
  for (int d = 32; d > 0; d >>= 1) v += __shfl_xor(v, d, 64);
  return v;
}
__device__ __forceinline__ int wave_reduce_sum_i(int v){
  #pragma unroll
  for (int d = 32; d > 0; d >>= 1) v += __shfl_xor(v, d, 64);
  return v;
}
__device__ __forceinline__ int wave_incl_scan_i(int v, int lane){
  #pragma unroll
  for (int d = 1; d < 64; d <<= 1){
    int u = __shfl_up(v, d, 64);
    if (lane >= d) v += u;
  }
  return v;
}
__device__ __forceinline__ unsigned short f2bf(float x){
  union { float f; unsigned u; } v; v.f = x;
  unsigned r = v.u + 0x7fff + ((v.u >> 16) & 1);
  return (unsigned short)(r >> 16);
}

// Kernel A: h = x @ W^T + b  (8192x64 fp32), s_src[n], s_dst[n]
extern "C" __global__ void __launch_bounds__(256)
k_h(const float* __restrict__ x, const float* __restrict__ ww, const float* __restrict__ wb,
    const float* __restrict__ aw, float* __restrict__ h,
    float* __restrict__ ssrc, float* __restrict__ sdst){
  __shared__ float xs[4][NEMB];
  const int t = threadIdx.x, w = t >> 6, lane = t & 63;
  const int n0 = blockIdx.x * 4;
  ((float2*)&xs[0][0])[t] = ((const float2*)(x + (size_t)n0 * NEMB))[t];
  __syncthreads();
  const int n = n0 + w;
  const float4* w4 = (const float4*)(ww + (size_t)lane * NEMB);
  const float4* x4 = (const float4*)&xs[w][0];
  float acc = wb[lane];
  #pragma unroll
  for (int k = 0; k < NEMB/4; ++k){
    float4 a = x4[k]; float4 b = w4[k];
    acc = fmaf(a.x, b.x, acc);
    acc = fmaf(a.y, b.y, acc);
    acc = fmaf(a.z, b.z, acc);
    acc = fmaf(a.w, b.w, acc);
  }
  h[(size_t)n * F + lane] = acc;
  float vs = wave_reduce_sum_f(acc * aw[lane]);
  float vd = wave_reduce_sum_f(acc * aw[F + lane]);
  if (lane == 0){ ssrc[n] = vs; sdst[n] = vd; }
}

// Kernel A2: transpose h (fp32 [N][F]) -> ht (bf16 [F][N])
extern "C" __global__ void __launch_bounds__(256)
k_tr(const float* __restrict__ h, unsigned short* __restrict__ ht){
  __shared__ float tile[64][65];
  const int t = threadIdx.x;
  const int n0 = blockIdx.x * 64;
  #pragma unroll
  for (int s = 0; s < 4; ++s){
    const int r = s*16 + (t>>4);
    const int c = (t&15)*4;
    const float4 v = *(const float4*)(h + (size_t)(n0+r)*F + c);
    tile[r][c] = v.x; tile[r][c+1] = v.y; tile[r][c+2] = v.z; tile[r][c+3] = v.w;
  }
  __syncthreads();
  const int f = t >> 2, jq = t & 3;
  unsigned short buf[16];
  #pragma unroll
  for (int k = 0; k < 16; ++k) buf[k] = f2bf(tile[jq*16 + k][f]);
  *(uint4*)(ht + (size_t)f*N + n0 + jq*16)     = *(uint4*)&buf[0];
  *(uint4*)(ht + (size_t)f*N + n0 + jq*16 + 8) = *(uint4*)&buf[8];
}

// Kernel B: pack adj -> 16-bit masks + per-row counts
extern "C" __global__ void __launch_bounds__(256)
k_pack(const int* __restrict__ adj, unsigned short* __restrict__ bm, int* __restrict__ cnt){
  const int i = blockIdx.x, t = threadIdx.x;
  int total = 0;
  #pragma unroll
  for (int half = 0; half < 2; ++half){
    const int jb = half*4096 + t*16;
    const int4* p4 = (const int4*)(adj + (size_t)i*N + jb);
    unsigned m = 0;
    #pragma unroll
    for (int k = 0; k < 4; ++k){
      int4 a = p4[k];
      m |= (unsigned)(a.x > 0) << (k*4+0);
      m |= (unsigned)(a.y > 0) << (k*4+1);
      m |= (unsigned)(a.z > 0) << (k*4+2);
      m |= (unsigned)(a.w > 0) << (k*4+3);
    }
    bm[(size_t)i*NWRD + (jb>>4)] = (unsigned short)m;
    total += __popc(m);
  }
  total = wave_reduce_sum_i(total);
  __shared__ int ws_[4];
  if ((t & 63) == 0) ws_[t >> 6] = total;
  __syncthreads();
  if (t == 0) cnt[i] = ws_[0] + ws_[1] + ws_[2] + ws_[3];
}

// Kernel C: exclusive scan of 8192 counts -> row_base
extern "C" __global__ void __launch_bounds__(1024)
k_scan(const int* __restrict__ cnt, int* __restrict__ base){
  __shared__ int wsum[16];
  const int t = threadIdx.x, lane = t & 63, w = t >> 6;
  int4 aa = ((const int4*)cnt)[t * 2];
  int4 bb = ((const int4*)cnt)[t * 2 + 1];
  int v[8] = {aa.x, aa.y, aa.z, aa.w, bb.x, bb.y, bb.z, bb.w};
  int local = 0;
  #pragma unroll
  for (int k = 0; k < 8; ++k){ int tmp = v[k]; v[k] = local; local += tmp; }
  int inc = wave_incl_scan_i(local, lane);
  int wexcl = inc - local;
  if (lane == 63) wsum[w] = inc;
  __syncthreads();
  if (t == 0){
    int run = 0;
    #pragma unroll
    for (int k = 0; k < 16; ++k){ int tmp = wsum[k]; wsum[k] = run; run += tmp; }
  }
  __syncthreads();
  const int b0 = wsum[w] + wexcl;
  ((int4*)base)[t * 2]     = make_int4(b0 + v[0], b0 + v[1], b0 + v[2], b0 + v[3]);
  ((int4*)base)[t * 2 + 1] = make_int4(b0 + v[4], b0 + v[5], b0 + v[6], b0 + v[7]);
}

// Kernel D: ranks + exp logits (no max-sub; logits bounded) -> bf16 p -> MFMA att@h -> elu
// Block: 256 thr (4 waves), BI=16 rows, chunk BJ=256 cols.
// Wave w owns output features w*16..w*16+15 via one 16x16x32 mfma chain.
extern "C" __global__ void __launch_bounds__(256, 3)
k_main(const unsigned short* __restrict__ bm, const unsigned short* __restrict__ ht,
       const float* __restrict__ ssrc, const float* __restrict__ sdst,
       const float* __restrict__ abias, const int* __restrict__ base,
       float* __restrict__ out){
  __shared__ __attribute__((aligned(16))) char ht_lds[64*512]; // [f][512B swizzled]
  __shared__ __attribute__((aligned(16))) char pt_lds[16*512]; // [i][512B swizzled]
  __shared__ float denom_lds[BI];
  const int t = threadIdx.x, w = t >> 6, lane = t & 63;
  const int i0 = blockIdx.x * BI;
  const int r = t >> 4, g = t & 15;       // p-production role: row r, col-group g
  const float ab = abias[0];
  int rank = base[i0 + r];
  float dsum = 0.f;
  f32x4 acc = {0.f, 0.f, 0.f, 0.f};

  const int fr = lane & 15, ks = lane >> 4;   // mfma fragment roles
  const int fB = w*16 + fr;
  const char* aBase = pt_lds + fr*512;
  const char* bBase = ht_lds + fB*512;
  const int sA = (fr & 7) << 4;
  const int sB = (fB & 7) << 4;

  for (int j0 = 0; j0 < N; j0 += BJ){
    __syncthreads();   // prior mfma reads done before overwrite
    // ---- stage ht chunk (bf16 [64][256], swizzled) via global_load_lds ----
    #pragma unroll
    for (int k = 0; k < 8; ++k){
      const int L = (w*8 + k) * 1024;
      const int f = (w*8 + k) * 2 + (lane >> 5);
      const int b = (lane & 31) * 16;
      const char* src = (const char*)ht + (size_t)f*(N*2) + j0*2 + (b ^ ((f & 7) << 4));
      __builtin_amdgcn_global_load_lds((const __attribute__((address_space(1))) void*)src,
                                       (__attribute__((address_space(3))) void*)(ht_lds + L),
                                       16, 0, 0);
    }
    // ---- p production: mask word -> ranks -> exp logits -> bf16 -> pt_lds ----
    {
      const unsigned m = bm[(size_t)(i0 + r)*NWRD + (j0 >> 4) + g];
      const int c = __popc(m);
      int inc = c;
      #pragma unroll
      for (int d = 1; d < 16; d <<= 1){
        int u = __shfl_up(inc, d, 16);
        if (g >= d) inc += u;
      }
      const int rowtot = __shfl(inc, 15, 16);
      int q = rank + inc - c;
      rank += rowtot;
      unsigned pk[8];
      #pragma unroll
      for (int bb = 0; bb < 16; ++bb){
        float p = 0.f;
        if ((m >> bb) & 1u){
          float e = ssrc[q >> 13] + sdst[q & (N - 1)] + ab;
          e = (e > 0.f) ? e : LEAKY * e;
          p = __expf(e);
          dsum += p;
          ++q;
        }
        if (bb & 1) pk[bb >> 1] |= (unsigned)f2bf(p) << 16;
        else        pk[bb >> 1]  = (unsigned)f2bf(p);
      }
      char* pb = pt_lds + r*512;
      const int sw = (r & 7) << 4;
      *(uint4*)(pb + ((g*32)      ^ sw)) = make_uint4(pk[0], pk[1], pk[2], pk[3]);
      *(uint4*)(pb + ((g*32 + 16) ^ sw)) = make_uint4(pk[4], pk[5], pk[6], pk[7]);
    }
    __syncthreads();   // staging (vmcnt drained by barrier) + p writes visible
    // ---- MFMA: 8 K-steps of 16x16x32 ----
    #pragma unroll
    for (int kk = 0; kk < 8; ++kk){
      const int off = kk*64 + ks*16;
      bf16x8 av = *(const bf16x8*)(aBase + (off ^ sA));
      bf16x8 bv = *(const bf16x8*)(bBase + (off ^ sB));
      acc = __builtin_amdgcn_mfma_f32_16x16x32_bf16(av, bv, acc, 0, 0, 0);
    }
  }
  // ---- denominators: reduce dsum within each 16-lane row group ----
  #pragma unroll
  for (int d = 8; d > 0; d >>= 1) dsum += __shfl_xor(dsum, d, 16);
  if (g == 0) denom_lds[r] = dsum;
  __syncthreads();
  // ---- epilogue: C/D layout col=lane&15, row=(lane>>4)*4+reg ----
  #pragma unroll
  for (int reg = 0; reg < 4; ++reg){
    const int il = ks*4 + reg;
    const float dn = denom_lds[il];
    float v = (dn > 0.f) ? acc[reg] / dn : 0.f;
    const float o = (v > 0.f) ? v : (__expf(v) - 1.f);
    out[(size_t)(i0 + il)*F + w*16 + fr] = o;
  }
}

extern "C" void kernel_launch(void* const* d_in, const int* in_sizes, int n_in,
                              void* d_out, int out_size, void* d_ws, size_t ws_size,
                              hipStream_t stream){
  const float* x   = (const float*)d_in[0];
  const int*   adj = (const int*)d_in[1];
  const float* ww  = (const float*)d_in[2];
  const float* wb  = (const float*)d_in[3];
  const float* aw  = (const float*)d_in[4];
  const float* ab  = (const float*)d_in[5];
  float* out = (float*)d_out;

  char* ws = (char*)d_ws;
  float*          h    = (float*)(ws);                                  // 2 MB
  unsigned short* ht   = (unsigned short*)(ws + (size_t)N*F*4);         // 1 MB
  float*          ssrc = (float*)(ws + (size_t)N*F*4 + (size_t)N*F*2);  // 32 KB
  float*          sdst = ssrc + N;                                      // 32 KB
  int*            cnt  = (int*)(sdst + N);                              // 32 KB
  int*            base = cnt + N;                                       // 32 KB
  unsigned short* bm   = (unsigned short*)(base + N);                   // 8 MB

  k_h   <<<N/4,  256, 0, stream>>>(x, ww, wb, aw, h, ssrc, sdst);
  k_tr  <<<N/64, 256, 0, stream>>>(h, ht);
  k_pack<<<N,    256, 0, stream>>>(adj, bm, cnt);
  k_scan<<<1,   1024, 0, stream>>>(cnt, base);
  k_main<<<N/BI, 256, 0, stream>>>(bm, ht, ssrc, sdst, ab, base, out);
}